// Round 1
// baseline (596.947 us; speedup 1.0000x reference)
//
#include <hip/hip_runtime.h>
#include <hip/hip_bf16.h>

#define VOCAB 50257
#define NB    2048
#define NE    128
#define NCH   393   // ceil(VOCAB/128)

typedef __bf16 bf16x8 __attribute__((ext_vector_type(8)));
typedef float  f32x4  __attribute__((ext_vector_type(4)));

// ---------------- kernel 1: recover indices from one-hot ----------------
__global__ void k_find_idx(const float4* __restrict__ oh, int* __restrict__ idx, long n4) {
  long stride = (long)gridDim.x * blockDim.x;
  for (long i = (long)blockIdx.x * blockDim.x + threadIdx.x; i < n4; i += stride) {
    float4 v = oh[i];
    if (v.x != 0.f || v.y != 0.f || v.z != 0.f || v.w != 0.f) {
      long j = i << 2;
      if (v.x != 0.f) { long p = j;     int b = (int)(p / VOCAB); idx[b] = (int)(p - (long)b * VOCAB); }
      if (v.y != 0.f) { long p = j + 1; int b = (int)(p / VOCAB); idx[b] = (int)(p - (long)b * VOCAB); }
      if (v.z != 0.f) { long p = j + 2; int b = (int)(p / VOCAB); idx[b] = (int)(p - (long)b * VOCAB); }
      if (v.w != 0.f) { long p = j + 3; int b = (int)(p / VOCAB); idx[b] = (int)(p - (long)b * VOCAB); }
    }
  }
}

// ---------------- kernel 2: w2 [128][V] f32 -> w2T [V][128] bf16 ----------------
__global__ void k_transpose(const float* __restrict__ w2, __hip_bfloat16* __restrict__ w2T) {
  __shared__ __hip_bfloat16 tile[64][130];
  const int v0 = blockIdx.x * 64;
  const int tv = threadIdx.x & 63;
  const int te = threadIdx.x >> 6;   // 0..3
  const int v  = v0 + tv;
#pragma unroll
  for (int e0 = 0; e0 < NE; e0 += 4) {
    int e = e0 + te;
    float val = (v < VOCAB) ? w2[(long)e * VOCAB + v] : 0.f;
    tile[tv][e] = __float2bfloat16(val);
  }
  __syncthreads();
  // write out: 64 rows x 128 bf16, 4B per thread per iter
#pragma unroll
  for (int it = 0; it < 16; ++it) {
    int f  = it * 256 + threadIdx.x;
    int r  = f >> 6;       // 0..63
    int c2 = f & 63;       // ushort2 index 0..63
    int vv = v0 + r;
    if (vv < VOCAB) {
      ushort2 p;
      p.x = *reinterpret_cast<const unsigned short*>(&tile[r][2 * c2]);
      p.y = *reinterpret_cast<const unsigned short*>(&tile[r][2 * c2 + 1]);
      reinterpret_cast<ushort2*>(w2T + (long)vv * NE)[c2] = p;
    }
  }
}

// ---------------- kernel 3: z1[b] = bf16(w1[idx[b]]) ----------------
__global__ void k_gather(const float* __restrict__ w1, const int* __restrict__ idx,
                         __hip_bfloat16* __restrict__ z1) {
  int t = blockIdx.x * blockDim.x + threadIdx.x;   // NB*NE threads
  int b = t >> 7, e = t & 127;
  z1[t] = __float2bfloat16(w1[(long)idx[b] * NE + e]);
}

// ---------------- GEMM: z1[2048x128] x w2T^T -> z2, LSE or OUT epilogue ----------------
template <bool LSE_PASS>
__global__ __launch_bounds__(256) void k_gemm(
    const __hip_bfloat16* __restrict__ z1,
    const __hip_bfloat16* __restrict__ w2T,
    const float* __restrict__ lse,
    float* __restrict__ pmax, float* __restrict__ psum,
    float* __restrict__ out) {
  __shared__ float sm[2][128];
  __shared__ float ss[2][128];
  const int lane = threadIdx.x & 63;
  const int wave = threadIdx.x >> 6;
  const int wm = wave >> 1, wn = wave & 1;
  const int l15 = lane & 15, lhi = lane >> 4;
  const int row0 = blockIdx.y * 128 + wm * 64;
  const int col0 = blockIdx.x * 128 + wn * 64;

  // A fragments: 4 row-frags x 4 k-blocks, each lane 8 bf16 (16B load)
  bf16x8 a[4][4];
  {
    const __hip_bfloat16* zp = z1 + (row0 + l15) * NE + lhi * 8;
#pragma unroll
    for (int mi = 0; mi < 4; ++mi)
#pragma unroll
      for (int kb = 0; kb < 4; ++kb)
        a[mi][kb] = *reinterpret_cast<const bf16x8*>(zp + mi * 16 * NE + kb * 32);
  }

  f32x4 acc[4][4];
#pragma unroll
  for (int mi = 0; mi < 4; ++mi)
#pragma unroll
    for (int ni = 0; ni < 4; ++ni)
      acc[mi][ni] = (f32x4){0.f, 0.f, 0.f, 0.f};

#pragma unroll
  for (int ni = 0; ni < 4; ++ni) {
    int col  = col0 + ni * 16 + l15;
    int colc = col < VOCAB ? col : VOCAB - 1;
    const __hip_bfloat16* wp = w2T + (long)colc * NE + lhi * 8;
#pragma unroll
    for (int kb = 0; kb < 4; ++kb) {
      bf16x8 b = *reinterpret_cast<const bf16x8*>(wp + kb * 32);
#pragma unroll
      for (int mi = 0; mi < 4; ++mi)
        acc[mi][ni] = __builtin_amdgcn_mfma_f32_16x16x32_bf16(a[mi][kb], b, acc[mi][ni], 0, 0, 0);
    }
  }

  if constexpr (LSE_PASS) {
    // per-row (64-col chunk) max and sum(exp) within each wave
#pragma unroll
    for (int mi = 0; mi < 4; ++mi) {
#pragma unroll
      for (int reg = 0; reg < 4; ++reg) {
        float vals[4];
        float m = -INFINITY;
#pragma unroll
        for (int ni = 0; ni < 4; ++ni) {
          int col = col0 + ni * 16 + l15;
          float v = (col < VOCAB) ? acc[mi][ni][reg] : -INFINITY;
          vals[ni] = v;
          m = fmaxf(m, v);
        }
#pragma unroll
        for (int off = 1; off < 16; off <<= 1) m = fmaxf(m, __shfl_xor(m, off));
        float s = 0.f;
#pragma unroll
        for (int ni = 0; ni < 4; ++ni)
          s += (vals[ni] == -INFINITY) ? 0.f : __expf(vals[ni] - m);
#pragma unroll
        for (int off = 1; off < 16; off <<= 1) s += __shfl_xor(s, off);
        if (l15 == 0) {
          int lr = wm * 64 + mi * 16 + lhi * 4 + reg;
          sm[wn][lr] = m;
          ss[wn][lr] = s;
        }
      }
    }
    __syncthreads();
    if (threadIdx.x < 128) {
      int r = threadIdx.x;
      float m0 = sm[0][r], m1 = sm[1][r];
      float s0 = ss[0][r], s1 = ss[1][r];
      float M = fmaxf(m0, m1);
      float S = s0 * __expf(m0 - M) + s1 * __expf(m1 - M);
      long o = (long)blockIdx.x * NB + blockIdx.y * 128 + r;
      pmax[o] = M;
      psum[o] = S;
    }
  } else {
#pragma unroll
    for (int mi = 0; mi < 4; ++mi) {
      int rbase = row0 + mi * 16 + lhi * 4;
#pragma unroll
      for (int reg = 0; reg < 4; ++reg) {
        float l = lse[rbase + reg];
        long orow = (long)(rbase + reg) * VOCAB;
#pragma unroll
        for (int ni = 0; ni < 4; ++ni) {
          int col = col0 + ni * 16 + l15;
          if (col < VOCAB) out[orow + col] = acc[mi][ni][reg] - l;
        }
      }
    }
  }
}

// ---------------- merge chunk partials -> lse[b] ----------------
__global__ void k_lse_reduce(const float* __restrict__ pmax, const float* __restrict__ psum,
                             float* __restrict__ lse) {
  int b = blockIdx.x * blockDim.x + threadIdx.x;   // NB threads
  float M = -INFINITY;
  for (int c = 0; c < NCH; ++c) M = fmaxf(M, pmax[(long)c * NB + b]);
  float S = 0.f;
  for (int c = 0; c < NCH; ++c) S += psum[(long)c * NB + b] * __expf(pmax[(long)c * NB + b] - M);
  lse[b] = M + __logf(S);
}

extern "C" void kernel_launch(void* const* d_in, const int* in_sizes, int n_in,
                              void* d_out, int out_size, void* d_ws, size_t ws_size,
                              hipStream_t stream) {
  const float* one_hot = (const float*)d_in[0];
  const float* w1      = (const float*)d_in[1];
  const float* w2      = (const float*)d_in[2];
  float* out = (float*)d_out;

  char* ws = (char*)d_ws;
  // ws layout (bytes): idx[2048] | z1 bf16 [2048*128] | w2T bf16 [V*128] | pmax | psum | lse
  int*            idx = (int*)ws;                                   // 8192 B
  __hip_bfloat16* z1  = (__hip_bfloat16*)(ws + 8192);               // 524288 B
  __hip_bfloat16* w2T = (__hip_bfloat16*)(ws + 532480);             // 12865792 B
  float*          pmax = (float*)(ws + 13398272);                   // 3219456 B
  float*          psum = (float*)(ws + 16617728);                   // 3219456 B
  float*          lse  = (float*)(ws + 19837184);                   // 8192 B  -> total 19845376 B

  long n4 = ((long)NB * VOCAB) >> 2;   // divisible by 4
  k_find_idx<<<2048, 256, 0, stream>>>((const float4*)one_hot, idx, n4);
  k_transpose<<<(VOCAB + 63) / 64, 256, 0, stream>>>(w2, w2T);
  k_gather<<<NB * NE / 256, 256, 0, stream>>>(w1, idx, z1);
  k_gemm<true><<<dim3(NCH, NB / 128), 256, 0, stream>>>(z1, w2T, nullptr, pmax, psum, nullptr);
  k_lse_reduce<<<NB / 256, 256, 0, stream>>>(pmax, psum, lse);
  k_gemm<false><<<dim3(NCH, NB / 128), 256, 0, stream>>>(z1, w2T, lse, nullptr, nullptr, out);
}